// Round 4
// baseline (329.257 us; speedup 1.0000x reference)
//
#include <hip/hip_runtime.h>
#include <hip/hip_bf16.h>

#define M_TOK 8192
#define N_OUT 4096
#define K_IN  4096

typedef __attribute__((ext_vector_type(8))) short bf16x8;
typedef __attribute__((ext_vector_type(16))) float f32x16;
typedef unsigned short u16;

// fp32 -> bf16 RNE (finite inputs)
__device__ static inline u16 f2bf(float f) {
    union { float f; unsigned int u; } v; v.f = f;
    unsigned int u = v.u;
    u += 0x7FFFu + ((u >> 16) & 1u);
    return (u16)(u >> 16);
}

__device__ static inline void load_lds16(const void* g, void* l) {
    __builtin_amdgcn_global_load_lds(
        (const __attribute__((address_space(1))) unsigned int*)g,
        (__attribute__((address_space(3))) unsigned int*)l,
        16, 0, 0);
}

// ---------------- fused prep pass (memory-bound, ~HBM roofline) -----------
__global__ void prep_kernel(const float* __restrict__ x,
                            const float* __restrict__ mean,
                            const float* __restrict__ sigma,
                            const float* __restrict__ noise,
                            const int* __restrict__ smult,
                            u16* __restrict__ xb, u16* __restrict__ wb) {
    if (blockIdx.x < 2048) {
        const int n4 = (M_TOK * K_IN) / 4;
        int i = blockIdx.x * blockDim.x + threadIdx.x;
        const int stride = 2048 * 256;
        for (int e = i; e < n4; e += stride) {
            float4 v = reinterpret_cast<const float4*>(x)[e];
            ushort4 o;
            o.x = f2bf(v.x); o.y = f2bf(v.y); o.z = f2bf(v.z); o.w = f2bf(v.w);
            reinterpret_cast<ushort4*>(xb)[e] = o;
        }
    } else {
        const float sm = (float)(*smult);
        const int n4 = (N_OUT * K_IN) / 4;
        int i = (blockIdx.x - 2048) * blockDim.x + threadIdx.x;
        const int stride = 1024 * 256;
        for (int e = i; e < n4; e += stride) {
            float4 m = reinterpret_cast<const float4*>(mean)[e];
            float4 s = reinterpret_cast<const float4*>(sigma)[e];
            float4 z = reinterpret_cast<const float4*>(noise)[e];
            ushort4 o;
            o.x = f2bf(m.x * (1.0f + z.x * fabsf(s.x) * sm));
            o.y = f2bf(m.y * (1.0f + z.y * fabsf(s.y) * sm));
            o.z = f2bf(m.z * (1.0f + z.z * fabsf(s.z) * sm));
            o.w = f2bf(m.w * (1.0f + z.w * fabsf(s.w) * sm));
            reinterpret_cast<ushort4*>(wb)[e] = o;
        }
    }
}

// ------- 256x256 GEMM, 32x32x16 MFMA, 1-barrier phases, frag pipeline ------
// C[t][o] = sum_k A[t][k]*B[o][k] + bias[o]; A=[M][K] bf16, B=[N][K] bf16.
// LDS: [buf(2)][A | B][half(2)][8192 elem] = 128 KiB. 16B-slot swizzle
// slot^=(row&7) applied on global src of global_load_lds + on ds_read.
// Per phase: issue next-phase frag ds_reads + 1 half-stage, sched_barrier,
// 8 MFMA (compiler inserts counted lgkm waits), vmcnt(2) at P2/P6, barrier.

#define BAR()    __builtin_amdgcn_s_barrier()
#define SCHED0() __builtin_amdgcn_sched_barrier(0)
#define VMC4()  asm volatile("s_waitcnt vmcnt(4)" ::: "memory")
#define VMC2()  asm volatile("s_waitcnt vmcnt(2)" ::: "memory")
#define VMC0()  asm volatile("s_waitcnt vmcnt(0)" ::: "memory")

#define LD_A(DST, PAIR, AB) \
  _Pragma("unroll") for (int mt_ = 0; mt_ < 2; ++mt_) \
  _Pragma("unroll") for (int kc_ = 0; kc_ < 4; ++kc_) \
    DST[mt_][kc_] = *reinterpret_cast<const bf16x8*>( \
      (AB) + (((PAIR)*2 + mt_)*32 + r31)*64 + koffE[kc_]);

#define LD_B(DST, NTT, BB) \
  _Pragma("unroll") for (int kc_ = 0; kc_ < 4; ++kc_) \
    DST[kc_] = *reinterpret_cast<const bf16x8*>( \
      (BB) + ((NTT)*32 + r31)*64 + koffE[kc_]);

#define OCT(MP, NTT, AR, BR) \
  __builtin_amdgcn_s_setprio(1); \
  _Pragma("unroll") for (int kc_ = 0; kc_ < 4; ++kc_) \
  _Pragma("unroll") for (int mt_ = 0; mt_ < 2; ++mt_) \
    acc[(MP)*2 + mt_][NTT] = __builtin_amdgcn_mfma_f32_32x32x16_bf16( \
      AR[mt_][kc_], BR[kc_], acc[(MP)*2 + mt_][NTT], 0, 0, 0); \
  __builtin_amdgcn_s_setprio(0);

#define STAGE_A(T, H, BUF) { \
  const u16* g_ = Abase + (size_t)((H)*128 + srow) * K_IN + (T)*64 + sxcol; \
  load_lds16(g_, smem + (BUF)*32768 + (H)*8192 + tid*8); \
  load_lds16(g_ + (size_t)64*K_IN, smem + (BUF)*32768 + (H)*8192 + 4096 + tid*8); }

#define STAGE_B(T, H, BUF) { \
  const u16* g_ = Bbase + (size_t)((H)*128 + srow) * K_IN + (T)*64 + sxcol; \
  load_lds16(g_, smem + (BUF)*32768 + 16384 + (H)*8192 + tid*8); \
  load_lds16(g_ + (size_t)64*K_IN, smem + (BUF)*32768 + 16384 + (H)*8192 + 4096 + tid*8); }

__global__ __launch_bounds__(512, 2)
void gemm_bias_kernel(const u16* __restrict__ A, const u16* __restrict__ B,
                      const float* __restrict__ bias, float* __restrict__ C) {
    __shared__ u16 smem[65536];   // 128 KiB

    const int tid  = threadIdx.x;
    const int lane = tid & 63;
    const int wid  = tid >> 6;
    const int wm   = wid >> 2;       // 0..1  (M half, 128 rows)
    const int wn   = wid & 3;        // 0..3  (N slice, 64 cols)
    const int r31  = lane & 31;
    const int hi5  = lane >> 5;
    const int xr   = lane & 7;

    // T1 v2: per-XCD 2D rectangle (round 3, kept: FETCH 197 MB)
    const int bid = blockIdx.x;
    const int xcd = bid & 7;
    const int c   = bid >> 3;
    const int r   = c >> 5;
    const int s   = c & 31;
    const int bm  = xcd * 4 + (s & 3);
    const int bn  = r * 8 + (s >> 2);
    const int brow = bm * 256;
    const int bcol = bn * 256;

    const u16* Abase = A + (size_t)brow * K_IN;
    const u16* Bbase = B + (size_t)bcol * K_IN;

    // staging swizzle (unchanged, measured 0 conflicts)
    const int srow  = tid >> 3;
    const int sxcol = ((tid & 7) ^ (srow & 7)) * 8;

    // ds_read swizzled k-slot offsets (elements), kc=0..3
    int koffE[4];
    #pragma unroll
    for (int kc = 0; kc < 4; ++kc)
        koffE[kc] = ((kc * 2 + hi5) ^ xr) * 8;

    const u16* A0 = smem +         wm * 8192;
    const u16* A1 = smem + 32768 + wm * 8192;
    const u16* B0 = smem +         16384 + (wn >> 1) * 8192 + (wn & 1) * 4096;
    const u16* B1 = smem + 32768 + 16384 + (wn >> 1) * 8192 + (wn & 1) * 4096;

    f32x16 acc[4][2];
    #pragma unroll
    for (int m = 0; m < 4; ++m)
        #pragma unroll
        for (int n = 0; n < 2; ++n)
            #pragma unroll
            for (int e = 0; e < 16; ++e)
                acc[m][n][e] = 0.f;

    bf16x8 aRe[2][4], aRo[2][4], bA0[4], bA1[4], bB[4];

    // Prologue: tile0 full -> buf0; B(1) -> buf1 (stays in flight)
    STAGE_B(0, 0, 0); STAGE_B(0, 1, 0);
    STAGE_A(0, 0, 0); STAGE_A(0, 1, 0);
    STAGE_B(1, 0, 1); STAGE_B(1, 1, 1);
    VMC4(); BAR();
    LD_A(aRe, 0, A0); LD_B(bA0, 0, B0);   // P0 operands

    for (int i = 0; i < 31; ++i) {
        const int t1 = 2 * i + 1, t2 = 2 * i + 2, t3 = 2 * i + 3;
        // P0: compute buf0 (mp0,nt0); issue bB(buf0,nt1); stage A(t1,h0)->buf1
        LD_B(bB, 1, B0); STAGE_A(t1, 0, 1);
        SCHED0(); OCT(0, 0, aRe, bA0); BAR();
        // P1: (mp0,nt1); issue aRo(buf0); stage A(t1,h1)
        LD_A(aRo, 1, A0); STAGE_A(t1, 1, 1);
        SCHED0(); OCT(0, 1, aRe, bB); BAR();
        // P2: (mp1,nt1); stage B(t2,h0)->buf0; gate A(t1)+B(t1) landed
        STAGE_B(t2, 0, 0);
        SCHED0(); OCT(1, 1, aRo, bB); VMC2(); BAR();
        // P3: (mp1,nt0); issue aRe+bA1 (buf1); stage B(t2,h1)
        LD_A(aRe, 0, A1); LD_B(bA1, 0, B1); STAGE_B(t2, 1, 0);
        SCHED0(); OCT(1, 0, aRo, bA0); BAR();
        // P4: buf1 (mp0,nt0); issue bB(buf1); stage A(t2,h0)->buf0
        LD_B(bB, 1, B1); STAGE_A(t2, 0, 0);
        SCHED0(); OCT(0, 0, aRe, bA1); BAR();
        // P5: (mp0,nt1); issue aRo(buf1); stage A(t2,h1)
        LD_A(aRo, 1, A1); STAGE_A(t2, 1, 0);
        SCHED0(); OCT(0, 1, aRe, bB); BAR();
        // P6: (mp1,nt1); stage B(t3,h0)->buf1; gate A(t2)+B(t2) landed
        STAGE_B(t3, 0, 1);
        SCHED0(); OCT(1, 1, aRo, bB); VMC2(); BAR();
        // P7: (mp1,nt0); issue aRe+bA0 (buf0, next tile); stage B(t3,h1)
        LD_A(aRe, 0, A0); LD_B(bA0, 0, B0); STAGE_B(t3, 1, 1);
        SCHED0(); OCT(1, 0, aRo, bA1); BAR();
    }

    // Tail: tiles 62 (buf0) and 63 (buf1); only A(63) left to stage
    LD_B(bB, 1, B0); STAGE_A(63, 0, 1);
    SCHED0(); OCT(0, 0, aRe, bA0); BAR();
    LD_A(aRo, 1, A0); STAGE_A(63, 1, 1);
    SCHED0(); OCT(0, 1, aRe, bB); BAR();
    SCHED0(); OCT(1, 1, aRo, bB); VMC0(); BAR();
    LD_A(aRe, 0, A1); LD_B(bA1, 0, B1);
    SCHED0(); OCT(1, 0, aRo, bA0); BAR();
    LD_B(bB, 1, B1);
    SCHED0(); OCT(0, 0, aRe, bA1); BAR();
    LD_A(aRo, 1, A1);
    SCHED0(); OCT(0, 1, aRe, bB); BAR();
    SCHED0(); OCT(1, 1, aRo, bB); BAR();
    OCT(1, 0, aRo, bA1);

    // Epilogue: 32x32 C/D: col = lane&31, row = (reg&3)+8*(reg>>2)+4*hi5
    const int crow0 = brow + wm * 128;
    const int ccol0 = bcol + wn * 64;
    #pragma unroll
    for (int nt = 0; nt < 2; ++nt) {
        const int col = ccol0 + nt * 32 + r31;
        const float bv = bias[col];
        #pragma unroll
        for (int mt = 0; mt < 4; ++mt) {
            #pragma unroll
            for (int g = 0; g < 4; ++g) {
                #pragma unroll
                for (int rr = 0; rr < 4; ++rr) {
                    const int row = crow0 + mt * 32 + g * 8 + 4 * hi5 + rr;
                    C[(size_t)row * N_OUT + col] = acc[mt][nt][g * 4 + rr] + bv;
                }
            }
        }
    }
}

extern "C" void kernel_launch(void* const* d_in, const int* in_sizes, int n_in,
                              void* d_out, int out_size, void* d_ws, size_t ws_size,
                              hipStream_t stream) {
    const float* x     = (const float*)d_in[0];
    const float* mean  = (const float*)d_in[1];
    const float* sigma = (const float*)d_in[2];
    const float* bias  = (const float*)d_in[3];
    const float* noise = (const float*)d_in[4];
    const int*   smult = (const int*)d_in[5];
    float* out = (float*)d_out;

    const size_t x_elems = (size_t)M_TOK * K_IN;
    const size_t w_elems = (size_t)N_OUT * K_IN;
    const size_t need = (x_elems + w_elems) * sizeof(u16);
    if (ws_size < need) return;

    u16* xb = (u16*)d_ws;
    u16* wb = xb + x_elems;

    prep_kernel<<<3072, 256, 0, stream>>>(x, mean, sigma, noise, smult, xb, wb);
    gemm_bias_kernel<<<512, 512, 0, stream>>>(xb, wb, bias, out);
}